// Round 10
// baseline (395.624 us; speedup 1.0000x reference)
//
#include <hip/hip_runtime.h>
#include <hip/hip_bf16.h>
#include <math.h>

#define B_   4
#define N_   2048
#define D_   512
#define H_   8
#define DH_  64
#define C_   3
#define HID_ 1365
#define HIDP 1408          // padded HID (11 * 128)
#define ROWS_ (B_*N_)      // 8192
#define TD_  (3*D_)        // 1536

typedef __attribute__((ext_vector_type(8))) short short8;   // 8 bf16 = 4 VGPR
typedef __attribute__((ext_vector_type(4))) float floatx4;

#define MFMA16(a,b,c) __builtin_amdgcn_mfma_f32_16x16x32_bf16(a,b,c,0,0,0)

typedef __attribute__((address_space(3))) unsigned lds_u32;
typedef __attribute__((address_space(1))) unsigned glb_u32;

__device__ __forceinline__ short sh(float v){
  union { __hip_bfloat16 b; short s; } u;
  u.b = __float2bfloat16(v);
  return u.s;
}

// global-layout segment swizzle: within each 64-short k-block, 16B segment s -> s ^ (row&7)
__device__ __forceinline__ int swz(int col, int row){
  return (col & ~63) | (col & 7) | ((((col >> 3) & 7) ^ (row & 7)) << 3);
}

// async global->LDS stage: ROWS rows of PITCH shorts (16B-swizzled global layout assumed).
template<int ROWS, int PITCH>
__device__ __forceinline__ void stageG(short* __restrict__ lds,
    const short* __restrict__ g, int ldg, int t){
  const int LPR = PITCH/8;          // lanes per row
  const int RPI = 64/LPR;           // rows per instruction
  const int PW  = (ROWS/RPI)/4;     // instructions per wave
  int lane = t & 63, w = t >> 6;
  #pragma unroll
  for (int i = 0; i < PW; ++i){
    int r0  = (w*PW + i)*RPI;
    int row = r0 + lane/LPR;
    const short* ga = g + (size_t)row*ldg + (lane % LPR)*8;
    short* la = lds + r0*PITCH;     // wave-uniform; HW adds lane*16B
    __builtin_amdgcn_global_load_lds((const glb_u32*)ga, (lds_u32*)la, 16, 0, 0);
  }
}

// MFMA fragment from unpadded swizzled LDS tile
__device__ __forceinline__ short8 fragS(const short* __restrict__ lds, int pitch,
    int mbase, int lane, int kk){
  int row  = mbase + (lane & 15);
  int seg  = (kk >> 3) + (lane >> 4);
  int phys = seg ^ (row & 7);
  return *(const short8*)(lds + row*pitch + phys*8);
}

// ---------------- merged: weight transpose-convert (swizzled) + coord proj + LN1 ----------------
__global__ __launch_bounds__(256) void convT_all(
    const float* __restrict__ Wqkv, const float* __restrict__ Wo,
    const float* __restrict__ W1, const float* __restrict__ W2,
    const float* __restrict__ W3,
    short* __restrict__ Wtqkv, short* __restrict__ Wto,
    short* __restrict__ Wt1, short* __restrict__ Wt2, short* __restrict__ Wt3,
    const float* __restrict__ coords, const float* __restrict__ Wc,
    float* __restrict__ tu,
    const float* __restrict__ x, const float* __restrict__ ln1_w,
    const float* __restrict__ ln1_b, short* __restrict__ h){
  int id = blockIdx.x;
  int t = threadIdx.x;
  if (id >= 3392){            // ---- LN1 rows ----
    int row = id - 3392;
    size_t base = (size_t)row * D_;
    float v0 = x[base + t];
    float v1 = x[base + t + 256];
    float s  = v0 + v1;
    float s2 = v0*v0 + v1*v1;
    #pragma unroll
    for (int off = 32; off >= 1; off >>= 1){
      s  += __shfl_xor(s,  off, 64);
      s2 += __shfl_xor(s2, off, 64);
    }
    __shared__ float red[8];
    int lane = t & 63, wv = t >> 6;
    if (lane == 0){ red[wv] = s; red[4+wv] = s2; }
    __syncthreads();
    float sum  = red[0]+red[1]+red[2]+red[3];
    float sum2 = red[4]+red[5]+red[6]+red[7];
    float mean = sum * (1.0f/D_);
    float var  = sum2 * (1.0f/D_) - mean*mean;
    float inv  = rsqrtf(fmaxf(var, 0.f) + 1e-5f);
    h[base + swz(t,     row)] = sh((v0-mean)*inv*ln1_w[t]     + ln1_b[t]);
    h[base + swz(t+256, row)] = sh((v1-mean)*inv*ln1_w[t+256] + ln1_b[t+256]);
    return;
  }
  if (id >= 3136){            // ---- coord projection: tu = (coords·Wc) * log2(e) ----
    int idx = (id - 3136)*256 + t;
    int n = idx & (N_-1);
    int hh = (idx >> 11) & (H_-1);
    int b = idx >> 14;
    float s = 0.f;
    #pragma unroll
    for (int cc = 0; cc < C_; ++cc)
      s += coords[((size_t)(b*N_+n))*C_ + cc] * Wc[cc*H_ + hh];
    tu[idx] = s * 1.44269504f;
    return;
  }
  // ---- weight transpose-convert ----
  __shared__ float tile[32][33];
  const float* in; short* out; int K, NN, Kp, nx;
  if (id < 768)      { in=Wqkv; out=Wtqkv; K=512;  NN=1536; Kp=512;  nx=48; }
  else if (id < 1024){ in=Wo;   out=Wto;   K=512;  NN=512;  Kp=512;  nx=16; id-=768; }
  else if (id < 1728){ in=W1;   out=Wt1;   K=512;  NN=HID_; Kp=512;  nx=44; id-=1024; }
  else if (id < 2432){ in=W2;   out=Wt2;   K=512;  NN=HID_; Kp=512;  nx=44; id-=1728; }
  else               { in=W3;   out=Wt3;   K=HID_; NN=512;  Kp=HIDP; nx=16; id-=2432; }
  int nt0 = (id % nx)*32, kt0 = (id / nx)*32;
  int r = t >> 5, cc = t & 31;
  #pragma unroll
  for (int i=0;i<4;++i){
    int k = kt0 + i*8 + r, n = nt0 + cc;
    tile[i*8+r][cc] = (k<K && n<NN) ? in[(size_t)k*NN + n] : 0.f;
  }
  __syncthreads();
  #pragma unroll
  for (int i=0;i<4;++i){
    int n = nt0 + i*8 + r, k = kt0 + cc;
    out[(size_t)n*Kp + swz(k, n)] = sh(tile[cc][i*8+r]);
  }
}

// ---------------- LayerNorm (f32 in, swizzled bf16 out) ----------------
__global__ __launch_bounds__(256) void ln_kernel(const float* __restrict__ x,
        const float* __restrict__ w, const float* __restrict__ b,
        short* __restrict__ out){
  int row = blockIdx.x;
  size_t base = (size_t)row * D_;
  int t = threadIdx.x;
  float v0 = x[base + t];
  float v1 = x[base + t + 256];
  float s  = v0 + v1;
  float s2 = v0*v0 + v1*v1;
  #pragma unroll
  for (int off = 32; off >= 1; off >>= 1){
    s  += __shfl_xor(s,  off, 64);
    s2 += __shfl_xor(s2, off, 64);
  }
  __shared__ float red[8];
  int lane = t & 63, wv = t >> 6;
  if (lane == 0){ red[wv] = s; red[4+wv] = s2; }
  __syncthreads();
  float sum  = red[0]+red[1]+red[2]+red[3];
  float sum2 = red[4]+red[5]+red[6]+red[7];
  float mean = sum * (1.0f/D_);
  float var  = sum2 * (1.0f/D_) - mean*mean;
  float inv  = rsqrtf(fmaxf(var, 0.f) + 1e-5f);
  out[base + swz(t,     row)] = sh((v0-mean)*inv*w[t]     + b[t]);
  out[base + swz(t+256, row)] = sh((v1-mean)*inv*w[t+256] + b[t+256]);
}

// ---------------- QKV GEMM 128x128 -> qb/kb [bh][n][hd] swz, vbt [bh][hd][n] swz ----------------
__global__ __launch_bounds__(256) void qkv_gemm(
    const short* __restrict__ A, const short* __restrict__ Bt,
    const float* __restrict__ bias,
    short* __restrict__ qb, short* __restrict__ kb, short* __restrict__ vbt){
  __shared__ short As[128*64];
  __shared__ short Bs[128*64];
  int t = threadIdx.x;
  int lane = t & 63, w = t >> 6;
  int wr = (w >> 1) * 64, wc = (w & 1) * 64;
  int col0 = blockIdx.x * 128, row0 = blockIdx.y * 128;
  floatx4 acc[4][4];
  #pragma unroll
  for (int mt=0;mt<4;++mt)
    #pragma unroll
    for (int nt=0;nt<4;++nt) acc[mt][nt] = (floatx4){0.f,0.f,0.f,0.f};
  for (int k0 = 0; k0 < D_; k0 += 64){
    __syncthreads();
    stageG<128,64>(As, A  + (size_t)row0*D_ + k0, D_, t);
    stageG<128,64>(Bs, Bt + (size_t)col0*D_ + k0, D_, t);
    __syncthreads();
    #pragma unroll
    for (int kk = 0; kk < 64; kk += 32){
      short8 af[4], bf[4];
      #pragma unroll
      for (int mt=0;mt<4;++mt) af[mt] = fragS(As, 64, wr+mt*16, lane, kk);
      #pragma unroll
      for (int nt=0;nt<4;++nt) bf[nt] = fragS(Bs, 64, wc+nt*16, lane, kk);
      #pragma unroll
      for (int mt=0;mt<4;++mt)
        #pragma unroll
        for (int nt=0;nt<4;++nt)
          acc[mt][nt] = MFMA16(af[mt], bf[nt], acc[mt][nt]);
    }
  }
  int quad = lane >> 4, c = lane & 15;
  #pragma unroll
  for (int mt=0;mt<4;++mt){
    #pragma unroll
    for (int nt=0;nt<4;++nt){
      #pragma unroll
      for (int r=0;r<4;++r){
        int row = row0 + wr + mt*16 + quad*4 + r;
        int col = col0 + wc + nt*16 + c;
        float v = acc[mt][nt][r] + bias[col];
        int bidx = row >> 11, n = row & (N_-1);
        int which = col >> 9, d = col & (D_-1), hh = d >> 6, hd = d & 63;
        short sv = sh(v);
        if (which == 0)
          qb[(((size_t)(bidx*H_ + hh))*N_ + n)*DH_ + swz(hd, n)] = sv;
        else if (which == 1)
          kb[(((size_t)(bidx*H_ + hh))*N_ + n)*DH_ + swz(hd, n)] = sv;
        else  // V transposed: [bh][hd][n], n swizzled by hd
          vbt[(((size_t)(bidx*H_ + hh))*DH_ + hd)*N_ + swz(n, hd)] = sv;
      }
    }
  }
}

// ---------------- MFMA GEMM 128x64 tile, BK=64, out = acc + bias + resid (f32) ----------------
__global__ __launch_bounds__(256) void gemm64(
    const short* __restrict__ A, int lda,
    const short* __restrict__ Bt, int Ktot,
    const float* __restrict__ bias,
    const float* __restrict__ resid, float* __restrict__ outF){
  __shared__ short As[128*64];
  __shared__ short Bs[64*64];
  int t = threadIdx.x, lane = t & 63, w = t >> 6;
  int wr = w * 32;
  int col0 = blockIdx.x * 64, row0 = blockIdx.y * 128;
  floatx4 acc[2][4];
  #pragma unroll
  for (int mt=0;mt<2;++mt)
    #pragma unroll
    for (int nt=0;nt<4;++nt) acc[mt][nt] = (floatx4){0.f,0.f,0.f,0.f};
  for (int k0 = 0; k0 < Ktot; k0 += 64){
    __syncthreads();
    stageG<128,64>(As, A  + (size_t)row0*lda + k0, lda, t);
    stageG<64,64> (Bs, Bt + (size_t)col0*Ktot + k0, Ktot, t);
    __syncthreads();
    #pragma unroll
    for (int kk = 0; kk < 64; kk += 32){
      short8 af[2], bf[4];
      #pragma unroll
      for (int mt=0;mt<2;++mt) af[mt] = fragS(As, 64, wr+mt*16, lane, kk);
      #pragma unroll
      for (int nt=0;nt<4;++nt) bf[nt] = fragS(Bs, 64, nt*16, lane, kk);
      #pragma unroll
      for (int mt=0;mt<2;++mt)
        #pragma unroll
        for (int nt=0;nt<4;++nt)
          acc[mt][nt] = MFMA16(af[mt], bf[nt], acc[mt][nt]);
    }
  }
  int quad = lane >> 4, c = lane & 15;
  #pragma unroll
  for (int mt=0;mt<2;++mt){
    #pragma unroll
    for (int nt=0;nt<4;++nt){
      #pragma unroll
      for (int r=0;r<4;++r){
        int row = row0 + wr + mt*16 + quad*4 + r;
        int col = col0 + nt*16 + c;
        size_t idx = (size_t)row*D_ + col;
        outF[idx] = acc[mt][nt][r] + bias[col] + resid[idx];
      }
    }
  }
}

// ---------------- fused SwiGLU gate GEMM: 128x128 tile, dual-B, swizzled out ----------------
__global__ __launch_bounds__(256) void gate_gemm(
    const short* __restrict__ A,
    const short* __restrict__ Bt1, const short* __restrict__ Bt2,
    const float* __restrict__ b1, const float* __restrict__ b2,
    short* __restrict__ ff){
  __shared__ short As[128*64];
  __shared__ short B1s[128*64];
  __shared__ short B2s[128*64];
  int t = threadIdx.x, lane = t & 63, w = t >> 6;
  int wr = (w >> 1) * 64, wc = (w & 1) * 64;
  int col0 = blockIdx.x * 128, row0 = blockIdx.y * 128;
  floatx4 a1[4][4], a2[4][4];
  #pragma unroll
  for (int mt=0;mt<4;++mt)
    #pragma unroll
    for (int nt=0;nt<4;++nt){
      a1[mt][nt] = (floatx4){0.f,0.f,0.f,0.f};
      a2[mt][nt] = (floatx4){0.f,0.f,0.f,0.f};
    }
  for (int k0 = 0; k0 < D_; k0 += 64){
    __syncthreads();
    stageG<128,64>(As,  A   + (size_t)row0*D_ + k0, D_, t);
    stageG<128,64>(B1s, Bt1 + (size_t)col0*D_ + k0, D_, t);
    stageG<128,64>(B2s, Bt2 + (size_t)col0*D_ + k0, D_, t);
    __syncthreads();
    #pragma unroll
    for (int kk = 0; kk < 64; kk += 32){
      short8 af[4], f1[4], f2[4];
      #pragma unroll
      for (int mt=0;mt<4;++mt) af[mt] = fragS(As, 64, wr+mt*16, lane, kk);
      #pragma unroll
      for (int nt=0;nt<4;++nt){
        f1[nt] = fragS(B1s, 64, wc+nt*16, lane, kk);
        f2[nt] = fragS(B2s, 64, wc+nt*16, lane, kk);
      }
      #pragma unroll
      for (int mt=0;mt<4;++mt)
        #pragma unroll
        for (int nt=0;nt<4;++nt){
          a1[mt][nt] = MFMA16(af[mt], f1[nt], a1[mt][nt]);
          a2[mt][nt] = MFMA16(af[mt], f2[nt], a2[mt][nt]);
        }
    }
  }
  int quad = lane >> 4, c = lane & 15;
  #pragma unroll
  for (int mt=0;mt<4;++mt){
    #pragma unroll
    for (int nt=0;nt<4;++nt){
      #pragma unroll
      for (int r=0;r<4;++r){
        int row = row0 + wr + mt*16 + quad*4 + r;
        int col = col0 + wc + nt*16 + c;
        float g1 = a1[mt][nt][r] + (col < HID_ ? b1[col] : 0.f);
        float g2 = a2[mt][nt][r] + (col < HID_ ? b2[col] : 0.f);
        float sig = 1.f / (1.f + __expf(-g1));
        ff[(size_t)row*HIDP + swz(col, row)] = sh(g1*sig*g2);
      }
    }
  }
}

// ---------------- MFMA flash attention: 128 q x 128 key tiles (R7 shape), swizzled P ----------------
// P = exp2(s*0.125*log2e - u[m]) with u = t*log2e; l per-lane partials, one reduce at end.
__global__ __launch_bounds__(256) void attn_mfma(
    const short* __restrict__ qb, const short* __restrict__ kb,
    const short* __restrict__ vbt, const float* __restrict__ tu,
    short* __restrict__ o){
  __shared__ short Ks[128*64];    // [key][hd] swizzled
  __shared__ short Vt[64*128];    // [hd][key] swizzled
  __shared__ short Ps[128*128];   // [q][key] swizzle-on-write
  __shared__ float ush[128];
  int qt = blockIdx.x, h = blockIdx.y, b = blockIdx.z;
  int bh = b*H_ + h;
  int t = threadIdx.x, lane = t & 63, w = t >> 6;
  int quad = lane >> 4, c = lane & 15;
  // stage Q into Ps overlay (unpadded pitch 64, 16KB of the 32KB region), read to regs
  stageG<128,64>(Ps, qb + ((size_t)bh*N_ + qt*128)*DH_, DH_, t);
  __syncthreads();
  short8 qf[2][2];
  #pragma unroll
  for (int mt=0;mt<2;++mt)
    #pragma unroll
    for (int kh=0;kh<2;++kh)
      qf[mt][kh] = fragS(Ps, 64, w*32 + mt*16, lane, kh*32);

  floatx4 O[2][4];
  float l_i[2][4];
  #pragma unroll
  for (int mt=0;mt<2;++mt){
    #pragma unroll
    for (int nt=0;nt<4;++nt) O[mt][nt] = (floatx4){0.f,0.f,0.f,0.f};
    #pragma unroll
    for (int r=0;r<4;++r) l_i[mt][r] = 0.f;
  }
  const short* Kbase = kb  + (size_t)bh*N_*DH_;
  const short* Vbase = vbt + (size_t)bh*DH_*N_;

  for (int kt = 0; kt < N_/128; ++kt){
    __syncthreads();
    stageG<128,64>(Ks, Kbase + (size_t)kt*128*DH_, DH_, t);
    stageG<64,128>(Vt, Vbase + kt*128, N_, t);
    if (t < 128) ush[t] = tu[(size_t)bh*N_ + kt*128 + t];
    __syncthreads();

    // S = Q K^T  (wave w: q rows w*32..w*32+31; keys 0..127)
    floatx4 S[2][8];
    #pragma unroll
    for (int mt=0;mt<2;++mt)
      #pragma unroll
      for (int nt=0;nt<8;++nt) S[mt][nt] = (floatx4){0.f,0.f,0.f,0.f};
    #pragma unroll
    for (int kh=0;kh<2;++kh){
      short8 kf[8];
      #pragma unroll
      for (int nt=0;nt<8;++nt) kf[nt] = fragS(Ks, 64, nt*16, lane, kh*32);
      #pragma unroll
      for (int mt=0;mt<2;++mt)
        #pragma unroll
        for (int nt=0;nt<8;++nt)
          S[mt][nt] = MFMA16(qf[mt][kh], kf[nt], S[mt][nt]);
    }
    float u8[8];
    #pragma unroll
    for (int nt=0;nt<8;++nt) u8[nt] = ush[nt*16 + c];
    // P = exp2(s*0.18034 - u); l partials; P -> Ps swizzle-on-write (wave-private rows)
    #pragma unroll
    for (int mt=0;mt<2;++mt)
      #pragma unroll
      for (int r=0;r<4;++r){
        int prow = w*32 + mt*16 + quad*4 + r;
        #pragma unroll
        for (int nt=0;nt<8;++nt){
          float p = exp2f(fmaf(S[mt][nt][r], 0.18033688f, -u8[nt]));
          l_i[mt][r] += p;
          Ps[prow*128 + swz(nt*16 + c, prow)] = sh(p);
        }
      }
    asm volatile("s_waitcnt lgkmcnt(0)" ::: "memory");
    // O += P V
    #pragma unroll
    for (int kh=0;kh<4;++kh){
      short8 vf[4], pf[2];
      #pragma unroll
      for (int nt=0;nt<4;++nt) vf[nt] = fragS(Vt, 128, nt*16, lane, kh*32);
      #pragma unroll
      for (int mt=0;mt<2;++mt) pf[mt] = fragS(Ps, 128, w*32 + mt*16, lane, kh*32);
      #pragma unroll
      for (int mt=0;mt<2;++mt)
        #pragma unroll
        for (int nt=0;nt<4;++nt)
          O[mt][nt] = MFMA16(pf[mt], vf[nt], O[mt][nt]);
    }
  }
  // reduce l over the 16 lanes of each quad, scale, store (swizzled for wo-GEMM A)
  #pragma unroll
  for (int mt=0;mt<2;++mt){
    #pragma unroll
    for (int r=0;r<4;++r){
      float l = l_i[mt][r];
      #pragma unroll
      for (int off=1; off<16; off<<=1) l += __shfl_xor(l, off, 64);
      float invl = 1.f / l;
      int row = qt*128 + w*32 + mt*16 + quad*4 + r;
      #pragma unroll
      for (int nt=0;nt<4;++nt){
        int col = h*DH_ + nt*16 + c;
        o[((size_t)(b*N_ + row))*D_ + swz(col, row)] = sh(O[mt][nt][r]*invl);
      }
    }
  }
}

extern "C" void kernel_launch(void* const* d_in, const int* in_sizes, int n_in,
                              void* d_out, int out_size, void* d_ws, size_t ws_size,
                              hipStream_t stream){
  const float* x      = (const float*)d_in[0];
  const float* coords = (const float*)d_in[1];
  const float* ln1_w  = (const float*)d_in[2];
  const float* ln1_b  = (const float*)d_in[3];
  const float* ln2_w  = (const float*)d_in[4];
  const float* ln2_b  = (const float*)d_in[5];
  const float* Wqkv   = (const float*)d_in[6];
  const float* bqkv   = (const float*)d_in[7];
  const float* Wo     = (const float*)d_in[8];
  const float* bo     = (const float*)d_in[9];
  const float* Wc     = (const float*)d_in[10];
  // d_in[11] = bc: constant over softmax axis -> no effect on output
  const float* W1     = (const float*)d_in[12];
  const float* b1     = (const float*)d_in[13];
  const float* W2     = (const float*)d_in[14];
  const float* b2     = (const float*)d_in[15];
  const float* W3     = (const float*)d_in[16];
  const float* b3     = (const float*)d_in[17];

  // ws layout (peak 40.2 MB), all bf16 raw shorts; swizzled layouts as documented
  char* ws = (char*)d_ws;
  short* Wtqkv = (short*)(ws);                         // [1536][512]
  short* Wto   = (short*)(ws + 1572864);               // [512][512]
  short* Wt1   = (short*)(ws + 2097152);               // [1408][512]
  short* Wt2   = (short*)(ws + 3538944);               // [1408][512]
  short* Wt3   = (short*)(ws + 4980736);               // [512][1408]
  float* tu    = (float*)(ws + 6422528);               // [32][2048]  t * log2(e)
  short* h     = (short*)(ws + 6684672);               // [8192][512]
  short* qb    = (short*)(ws + 15073280);              // 8 MB
  short* kb    = (short*)(ws + 23461888);              // 8 MB
  short* vbt   = (short*)(ws + 31850496);              // 8 MB  [bh][hd][n]
  short* o     = h;                                    // alias: h dead after qkv
  short* h2    = h;                                    // alias: o dead after wo
  short* ff    = qb;                                   // alias: q/k/v dead after attn
  float* x1    = (float*)d_out;                        // f32 [8192][512] = d_out

  // blocks: [0,3136) weights, [3136,3392) coord proj, [3392,11584) LN1
  convT_all<<<dim3(11584), dim3(256), 0, stream>>>(Wqkv, Wo, W1, W2, W3,
      Wtqkv, Wto, Wt1, Wt2, Wt3, coords, Wc, tu, x, ln1_w, ln1_b, h);
  qkv_gemm<<<dim3(12,64), dim3(256), 0, stream>>>(h, Wtqkv, bqkv, qb, kb, vbt);
  attn_mfma<<<dim3(16,8,4), dim3(256), 0, stream>>>(qb, kb, vbt, tu, o);
  gemm64<<<dim3(8,64), dim3(256), 0, stream>>>(o, 512, Wto, 512, bo, x, x1);
  ln_kernel<<<dim3(ROWS_), dim3(256), 0, stream>>>(x1, ln2_w, ln2_b, h2);
  gate_gemm<<<dim3(11,64), dim3(256), 0, stream>>>(h2, Wt1, Wt2, b1, b2, ff);
  gemm64<<<dim3(8,64), dim3(256), 0, stream>>>(ff, HIDP, Wt3, HIDP, b3, x1, x1);
}

// Round 11
// 313.253 us; speedup vs baseline: 1.2630x; 1.2630x over previous
//
#include <hip/hip_runtime.h>
#include <hip/hip_bf16.h>
#include <math.h>

#define B_   4
#define N_   2048
#define D_   512
#define H_   8
#define DH_  64
#define C_   3
#define HID_ 1365
#define HIDP 1408          // padded HID (11 * 128)
#define ROWS_ (B_*N_)      // 8192
#define TD_  (3*D_)        // 1536

typedef __attribute__((ext_vector_type(8))) short short8;   // 8 bf16 = 4 VGPR
typedef __attribute__((ext_vector_type(4))) float floatx4;

#define MFMA16(a,b,c) __builtin_amdgcn_mfma_f32_16x16x32_bf16(a,b,c,0,0,0)

typedef __attribute__((address_space(3))) unsigned lds_u32;
typedef __attribute__((address_space(1))) unsigned glb_u32;

__device__ __forceinline__ short sh(float v){
  union { __hip_bfloat16 b; short s; } u;
  u.b = __float2bfloat16(v);
  return u.s;
}

// global-layout segment swizzle: within each 64-short k-block, 16B segment s -> s ^ (row&7)
__device__ __forceinline__ int swz(int col, int row){
  return (col & ~63) | (col & 7) | ((((col >> 3) & 7) ^ (row & 7)) << 3);
}

// async global->LDS stage: ROWS rows of PITCH shorts (16B-swizzled global layout assumed).
template<int ROWS, int PITCH>
__device__ __forceinline__ void stageG(short* __restrict__ lds,
    const short* __restrict__ g, int ldg, int t){
  const int LPR = PITCH/8;          // lanes per row
  const int RPI = 64/LPR;           // rows per instruction
  const int PW  = (ROWS/RPI)/4;     // instructions per wave
  int lane = t & 63, w = t >> 6;
  #pragma unroll
  for (int i = 0; i < PW; ++i){
    int r0  = (w*PW + i)*RPI;
    int row = r0 + lane/LPR;
    const short* ga = g + (size_t)row*ldg + (lane % LPR)*8;
    short* la = lds + r0*PITCH;     // wave-uniform; HW adds lane*16B
    __builtin_amdgcn_global_load_lds((const glb_u32*)ga, (lds_u32*)la, 16, 0, 0);
  }
}

// MFMA fragment from unpadded swizzled LDS tile
__device__ __forceinline__ short8 fragS(const short* __restrict__ lds, int pitch,
    int mbase, int lane, int kk){
  int row  = mbase + (lane & 15);
  int seg  = (kk >> 3) + (lane >> 4);
  int phys = seg ^ (row & 7);
  return *(const short8*)(lds + row*pitch + phys*8);
}

// MFMA fragment from padded (pitch 136) unswizzled LDS (ds_write path, P matrix)
__device__ __forceinline__ short8 fragP(const short* __restrict__ lds,
    int mbase, int lane, int kk){
  return *(const short8*)(lds + (mbase + (lane & 15))*136 + kk + ((lane >> 4) << 3));
}

// ---------------- merged: weight transpose-convert (swizzled) + coord proj + LN1 ----------------
__global__ __launch_bounds__(256) void convT_all(
    const float* __restrict__ Wqkv, const float* __restrict__ Wo,
    const float* __restrict__ W1, const float* __restrict__ W2,
    const float* __restrict__ W3,
    short* __restrict__ Wtqkv, short* __restrict__ Wto,
    short* __restrict__ Wt1, short* __restrict__ Wt2, short* __restrict__ Wt3,
    const float* __restrict__ coords, const float* __restrict__ Wc,
    float* __restrict__ tv,
    const float* __restrict__ x, const float* __restrict__ ln1_w,
    const float* __restrict__ ln1_b, short* __restrict__ h){
  int id = blockIdx.x;
  int t = threadIdx.x;
  if (id >= 3392){            // ---- LN1 rows ----
    int row = id - 3392;
    size_t base = (size_t)row * D_;
    float v0 = x[base + t];
    float v1 = x[base + t + 256];
    float s  = v0 + v1;
    float s2 = v0*v0 + v1*v1;
    #pragma unroll
    for (int off = 32; off >= 1; off >>= 1){
      s  += __shfl_xor(s,  off, 64);
      s2 += __shfl_xor(s2, off, 64);
    }
    __shared__ float red[8];
    int lane = t & 63, wv = t >> 6;
    if (lane == 0){ red[wv] = s; red[4+wv] = s2; }
    __syncthreads();
    float sum  = red[0]+red[1]+red[2]+red[3];
    float sum2 = red[4]+red[5]+red[6]+red[7];
    float mean = sum * (1.0f/D_);
    float var  = sum2 * (1.0f/D_) - mean*mean;
    float inv  = rsqrtf(fmaxf(var, 0.f) + 1e-5f);
    h[base + swz(t,     row)] = sh((v0-mean)*inv*ln1_w[t]     + ln1_b[t]);
    h[base + swz(t+256, row)] = sh((v1-mean)*inv*ln1_w[t+256] + ln1_b[t+256]);
    return;
  }
  if (id >= 3136){            // ---- coord projection: tv = coords·Wc ----
    int idx = (id - 3136)*256 + t;
    int n = idx & (N_-1);
    int hh = (idx >> 11) & (H_-1);
    int b = idx >> 14;
    float s = 0.f;
    #pragma unroll
    for (int cc = 0; cc < C_; ++cc)
      s += coords[((size_t)(b*N_+n))*C_ + cc] * Wc[cc*H_ + hh];
    tv[idx] = s;
    return;
  }
  // ---- weight transpose-convert ----
  __shared__ float tile[32][33];
  const float* in; short* out; int K, NN, Kp, nx;
  if (id < 768)      { in=Wqkv; out=Wtqkv; K=512;  NN=1536; Kp=512;  nx=48; }
  else if (id < 1024){ in=Wo;   out=Wto;   K=512;  NN=512;  Kp=512;  nx=16; id-=768; }
  else if (id < 1728){ in=W1;   out=Wt1;   K=512;  NN=HID_; Kp=512;  nx=44; id-=1024; }
  else if (id < 2432){ in=W2;   out=Wt2;   K=512;  NN=HID_; Kp=512;  nx=44; id-=1728; }
  else               { in=W3;   out=Wt3;   K=HID_; NN=512;  Kp=HIDP; nx=16; id-=2432; }
  int nt0 = (id % nx)*32, kt0 = (id / nx)*32;
  int r = t >> 5, cc = t & 31;
  #pragma unroll
  for (int i=0;i<4;++i){
    int k = kt0 + i*8 + r, n = nt0 + cc;
    tile[i*8+r][cc] = (k<K && n<NN) ? in[(size_t)k*NN + n] : 0.f;
  }
  __syncthreads();
  #pragma unroll
  for (int i=0;i<4;++i){
    int n = nt0 + i*8 + r, k = kt0 + cc;
    out[(size_t)n*Kp + swz(k, n)] = sh(tile[cc][i*8+r]);
  }
}

// ---------------- LayerNorm (f32 in, swizzled bf16 out) ----------------
__global__ __launch_bounds__(256) void ln_kernel(const float* __restrict__ x,
        const float* __restrict__ w, const float* __restrict__ b,
        short* __restrict__ out){
  int row = blockIdx.x;
  size_t base = (size_t)row * D_;
  int t = threadIdx.x;
  float v0 = x[base + t];
  float v1 = x[base + t + 256];
  float s  = v0 + v1;
  float s2 = v0*v0 + v1*v1;
  #pragma unroll
  for (int off = 32; off >= 1; off >>= 1){
    s  += __shfl_xor(s,  off, 64);
    s2 += __shfl_xor(s2, off, 64);
  }
  __shared__ float red[8];
  int lane = t & 63, wv = t >> 6;
  if (lane == 0){ red[wv] = s; red[4+wv] = s2; }
  __syncthreads();
  float sum  = red[0]+red[1]+red[2]+red[3];
  float sum2 = red[4]+red[5]+red[6]+red[7];
  float mean = sum * (1.0f/D_);
  float var  = sum2 * (1.0f/D_) - mean*mean;
  float inv  = rsqrtf(fmaxf(var, 0.f) + 1e-5f);
  out[base + swz(t,     row)] = sh((v0-mean)*inv*w[t]     + b[t]);
  out[base + swz(t+256, row)] = sh((v1-mean)*inv*w[t+256] + b[t+256]);
}

// ---------------- QKV GEMM 128x128 -> qb/kb [bh][n][hd] swz, vbt [bh][hd][n] swz ----------------
__global__ __launch_bounds__(256) void qkv_gemm(
    const short* __restrict__ A, const short* __restrict__ Bt,
    const float* __restrict__ bias,
    short* __restrict__ qb, short* __restrict__ kb, short* __restrict__ vbt){
  __shared__ short As[128*64];
  __shared__ short Bs[128*64];
  int t = threadIdx.x;
  int lane = t & 63, w = t >> 6;
  int wr = (w >> 1) * 64, wc = (w & 1) * 64;
  int col0 = blockIdx.x * 128, row0 = blockIdx.y * 128;
  floatx4 acc[4][4];
  #pragma unroll
  for (int mt=0;mt<4;++mt)
    #pragma unroll
    for (int nt=0;nt<4;++nt) acc[mt][nt] = (floatx4){0.f,0.f,0.f,0.f};
  for (int k0 = 0; k0 < D_; k0 += 64){
    __syncthreads();
    stageG<128,64>(As, A  + (size_t)row0*D_ + k0, D_, t);
    stageG<128,64>(Bs, Bt + (size_t)col0*D_ + k0, D_, t);
    __syncthreads();
    #pragma unroll
    for (int kk = 0; kk < 64; kk += 32){
      short8 af[4], bf[4];
      #pragma unroll
      for (int mt=0;mt<4;++mt) af[mt] = fragS(As, 64, wr+mt*16, lane, kk);
      #pragma unroll
      for (int nt=0;nt<4;++nt) bf[nt] = fragS(Bs, 64, wc+nt*16, lane, kk);
      #pragma unroll
      for (int mt=0;mt<4;++mt)
        #pragma unroll
        for (int nt=0;nt<4;++nt)
          acc[mt][nt] = MFMA16(af[mt], bf[nt], acc[mt][nt]);
    }
  }
  int quad = lane >> 4, c = lane & 15;
  #pragma unroll
  for (int mt=0;mt<4;++mt){
    #pragma unroll
    for (int nt=0;nt<4;++nt){
      #pragma unroll
      for (int r=0;r<4;++r){
        int row = row0 + wr + mt*16 + quad*4 + r;
        int col = col0 + wc + nt*16 + c;
        float v = acc[mt][nt][r] + bias[col];
        int bidx = row >> 11, n = row & (N_-1);
        int which = col >> 9, d = col & (D_-1), hh = d >> 6, hd = d & 63;
        short sv = sh(v);
        if (which == 0)
          qb[(((size_t)(bidx*H_ + hh))*N_ + n)*DH_ + swz(hd, n)] = sv;
        else if (which == 1)
          kb[(((size_t)(bidx*H_ + hh))*N_ + n)*DH_ + swz(hd, n)] = sv;
        else  // V transposed: [bh][hd][n], n swizzled by hd
          vbt[(((size_t)(bidx*H_ + hh))*DH_ + hd)*N_ + swz(n, hd)] = sv;
      }
    }
  }
}

// ---------------- MFMA GEMM 128x64 tile, BK=64, out = acc + bias + resid (f32) ----------------
__global__ __launch_bounds__(256) void gemm64(
    const short* __restrict__ A, int lda,
    const short* __restrict__ Bt, int Ktot,
    const float* __restrict__ bias,
    const float* __restrict__ resid, float* __restrict__ outF){
  __shared__ short As[128*64];
  __shared__ short Bs[64*64];
  int t = threadIdx.x, lane = t & 63, w = t >> 6;
  int wr = w * 32;
  int col0 = blockIdx.x * 64, row0 = blockIdx.y * 128;
  floatx4 acc[2][4];
  #pragma unroll
  for (int mt=0;mt<2;++mt)
    #pragma unroll
    for (int nt=0;nt<4;++nt) acc[mt][nt] = (floatx4){0.f,0.f,0.f,0.f};
  for (int k0 = 0; k0 < Ktot; k0 += 64){
    __syncthreads();
    stageG<128,64>(As, A  + (size_t)row0*lda + k0, lda, t);
    stageG<64,64> (Bs, Bt + (size_t)col0*Ktot + k0, Ktot, t);
    __syncthreads();
    #pragma unroll
    for (int kk = 0; kk < 64; kk += 32){
      short8 af[2], bf[4];
      #pragma unroll
      for (int mt=0;mt<2;++mt) af[mt] = fragS(As, 64, wr+mt*16, lane, kk);
      #pragma unroll
      for (int nt=0;nt<4;++nt) bf[nt] = fragS(Bs, 64, nt*16, lane, kk);
      #pragma unroll
      for (int mt=0;mt<2;++mt)
        #pragma unroll
        for (int nt=0;nt<4;++nt)
          acc[mt][nt] = MFMA16(af[mt], bf[nt], acc[mt][nt]);
    }
  }
  int quad = lane >> 4, c = lane & 15;
  #pragma unroll
  for (int mt=0;mt<2;++mt){
    #pragma unroll
    for (int nt=0;nt<4;++nt){
      #pragma unroll
      for (int r=0;r<4;++r){
        int row = row0 + wr + mt*16 + quad*4 + r;
        int col = col0 + nt*16 + c;
        size_t idx = (size_t)row*D_ + col;
        outF[idx] = acc[mt][nt][r] + bias[col] + resid[idx];
      }
    }
  }
}

// ---------------- fused SwiGLU gate GEMM: 128x64 tile, dual-B, swizzled out ----------------
__global__ __launch_bounds__(256) void gate_gemm(
    const short* __restrict__ A,
    const short* __restrict__ Bt1, const short* __restrict__ Bt2,
    const float* __restrict__ b1, const float* __restrict__ b2,
    short* __restrict__ ff){
  __shared__ short As[128*64];
  __shared__ short B1s[64*64];
  __shared__ short B2s[64*64];
  int t = threadIdx.x, lane = t & 63, w = t >> 6;
  int wr = (w >> 1) * 64, wc = (w & 1) * 32;
  int col0 = blockIdx.x * 64, row0 = blockIdx.y * 128;
  floatx4 a1[4][2], a2[4][2];
  #pragma unroll
  for (int mt=0;mt<4;++mt)
    #pragma unroll
    for (int nt=0;nt<2;++nt){
      a1[mt][nt] = (floatx4){0.f,0.f,0.f,0.f};
      a2[mt][nt] = (floatx4){0.f,0.f,0.f,0.f};
    }
  for (int k0 = 0; k0 < D_; k0 += 64){
    __syncthreads();
    stageG<128,64>(As, A + (size_t)row0*D_ + k0, D_, t);
    stageG<64,64>(B1s, Bt1 + (size_t)col0*D_ + k0, D_, t);
    stageG<64,64>(B2s, Bt2 + (size_t)col0*D_ + k0, D_, t);
    __syncthreads();
    #pragma unroll
    for (int kk = 0; kk < 64; kk += 32){
      short8 af[4], f1[2], f2[2];
      #pragma unroll
      for (int mt=0;mt<4;++mt) af[mt] = fragS(As, 64, wr+mt*16, lane, kk);
      #pragma unroll
      for (int nt=0;nt<2;++nt){
        f1[nt] = fragS(B1s, 64, wc+nt*16, lane, kk);
        f2[nt] = fragS(B2s, 64, wc+nt*16, lane, kk);
      }
      #pragma unroll
      for (int mt=0;mt<4;++mt)
        #pragma unroll
        for (int nt=0;nt<2;++nt){
          a1[mt][nt] = MFMA16(af[mt], f1[nt], a1[mt][nt]);
          a2[mt][nt] = MFMA16(af[mt], f2[nt], a2[mt][nt]);
        }
    }
  }
  int quad = lane >> 4, c = lane & 15;
  #pragma unroll
  for (int mt=0;mt<4;++mt){
    #pragma unroll
    for (int nt=0;nt<2;++nt){
      #pragma unroll
      for (int r=0;r<4;++r){
        int row = row0 + wr + mt*16 + quad*4 + r;
        int col = col0 + wc + nt*16 + c;
        float g1 = a1[mt][nt][r] + (col < HID_ ? b1[col] : 0.f);
        float g2 = a2[mt][nt][r] + (col < HID_ ? b2[col] : 0.f);
        float sig = 1.f / (1.f + __expf(-g1));
        ff[(size_t)row*HIDP + swz(col, row)] = sh(g1*sig*g2);
      }
    }
  }
}

// ---------------- MFMA flash attention: 128 q x 128 key tiles, fixed-max softmax ----------------
__global__ __launch_bounds__(256) void attn_mfma(
    const short* __restrict__ qb, const short* __restrict__ kb,
    const short* __restrict__ vbt, const float* __restrict__ tv,
    short* __restrict__ o){
  __shared__ short Ks[128*64];    // [key][hd] swizzled
  __shared__ short Vt[64*128];    // [hd][key] swizzled
  __shared__ short Ps[128*136];   // [q][key] padded, ds_write path
  __shared__ float tsh[128];
  int qt = blockIdx.x, h = blockIdx.y, b = blockIdx.z;
  int bh = b*H_ + h;
  int t = threadIdx.x, lane = t & 63, w = t >> 6;
  int quad = lane >> 4, c = lane & 15;
  // stage Q into Ps overlay (unpadded pitch 64), read to regs
  stageG<128,64>(Ps, qb + ((size_t)bh*N_ + qt*128)*DH_, DH_, t);
  __syncthreads();
  short8 qf[2][2];
  #pragma unroll
  for (int mt=0;mt<2;++mt)
    #pragma unroll
    for (int kh=0;kh<2;++kh)
      qf[mt][kh] = fragS(Ps, 64, w*32 + mt*16, lane, kh*32);

  floatx4 O[2][4];
  float l_i[2][4];
  #pragma unroll
  for (int mt=0;mt<2;++mt){
    #pragma unroll
    for (int nt=0;nt<4;++nt) O[mt][nt] = (floatx4){0.f,0.f,0.f,0.f};
    #pragma unroll
    for (int r=0;r<4;++r) l_i[mt][r] = 0.f;
  }
  const short* Kbase = kb  + (size_t)bh*N_*DH_;
  const short* Vbase = vbt + (size_t)bh*DH_*N_;

  for (int kt = 0; kt < N_/128; ++kt){
    __syncthreads();
    stageG<128,64>(Ks, Kbase + (size_t)kt*128*DH_, DH_, t);
    stageG<64,128>(Vt, Vbase + kt*128, N_, t);
    if (t < 128) tsh[t] = tv[(size_t)bh*N_ + kt*128 + t];
    __syncthreads();

    // S = Q K^T  (wave w: q rows w*32..w*32+31; keys 0..127)
    floatx4 S[2][8];
    #pragma unroll
    for (int mt=0;mt<2;++mt)
      #pragma unroll
      for (int nt=0;nt<8;++nt) S[mt][nt] = (floatx4){0.f,0.f,0.f,0.f};
    #pragma unroll
    for (int kh=0;kh<2;++kh){
      short8 kf[8];
      #pragma unroll
      for (int nt=0;nt<8;++nt) kf[nt] = fragS(Ks, 64, nt*16, lane, kh*32);
      #pragma unroll
      for (int mt=0;mt<2;++mt)
        #pragma unroll
        for (int nt=0;nt<8;++nt)
          S[mt][nt] = MFMA16(qf[mt][kh], kf[nt], S[mt][nt]);
    }
    float ts[8];
    #pragma unroll
    for (int nt=0;nt<8;++nt) ts[nt] = tsh[nt*16 + c];
    // P = exp(s/8 - t[m]); l partials; P -> Ps (wave-private rows)
    #pragma unroll
    for (int mt=0;mt<2;++mt)
      #pragma unroll
      for (int r=0;r<4;++r){
        #pragma unroll
        for (int nt=0;nt<8;++nt){
          float p = __expf(S[mt][nt][r]*0.125f - ts[nt]);
          l_i[mt][r] += p;
          Ps[(w*32 + mt*16 + quad*4 + r)*136 + nt*16 + c] = sh(p);
        }
      }
    asm volatile("s_waitcnt lgkmcnt(0)" ::: "memory");
    // O += P V
    #pragma unroll
    for (int kh=0;kh<4;++kh){
      short8 vf[4], pf[2];
      #pragma unroll
      for (int nt=0;nt<4;++nt) vf[nt] = fragS(Vt, 128, nt*16, lane, kh*32);
      #pragma unroll
      for (int mt=0;mt<2;++mt) pf[mt] = fragP(Ps, w*32 + mt*16, lane, kh*32);
      #pragma unroll
      for (int mt=0;mt<2;++mt)
        #pragma unroll
        for (int nt=0;nt<4;++nt)
          O[mt][nt] = MFMA16(pf[mt], vf[nt], O[mt][nt]);
    }
  }
  // reduce l over the 16 lanes of each quad, scale, store (swizzled for wo-GEMM A)
  #pragma unroll
  for (int mt=0;mt<2;++mt){
    #pragma unroll
    for (int r=0;r<4;++r){
      float l = l_i[mt][r];
      #pragma unroll
      for (int off=1; off<16; off<<=1) l += __shfl_xor(l, off, 64);
      float invl = 1.f / l;
      int row = qt*128 + w*32 + mt*16 + quad*4 + r;
      #pragma unroll
      for (int nt=0;nt<4;++nt){
        int col = h*DH_ + nt*16 + c;
        o[((size_t)(b*N_ + row))*D_ + swz(col, row)] = sh(O[mt][nt][r]*invl);
      }
    }
  }
}

extern "C" void kernel_launch(void* const* d_in, const int* in_sizes, int n_in,
                              void* d_out, int out_size, void* d_ws, size_t ws_size,
                              hipStream_t stream){
  const float* x      = (const float*)d_in[0];
  const float* coords = (const float*)d_in[1];
  const float* ln1_w  = (const float*)d_in[2];
  const float* ln1_b  = (const float*)d_in[3];
  const float* ln2_w  = (const float*)d_in[4];
  const float* ln2_b  = (const float*)d_in[5];
  const float* Wqkv   = (const float*)d_in[6];
  const float* bqkv   = (const float*)d_in[7];
  const float* Wo     = (const float*)d_in[8];
  const float* bo     = (const float*)d_in[9];
  const float* Wc     = (const float*)d_in[10];
  // d_in[11] = bc: constant over softmax axis -> no effect on output
  const float* W1     = (const float*)d_in[12];
  const float* b1     = (const float*)d_in[13];
  const float* W2     = (const float*)d_in[14];
  const float* b2     = (const float*)d_in[15];
  const float* W3     = (const float*)d_in[16];
  const float* b3     = (const float*)d_in[17];

  // ws layout (peak 40.2 MB), all bf16 raw shorts; swizzled layouts as documented
  char* ws = (char*)d_ws;
  short* Wtqkv = (short*)(ws);                         // [1536][512]
  short* Wto   = (short*)(ws + 1572864);               // [512][512]
  short* Wt1   = (short*)(ws + 2097152);               // [1408][512]
  short* Wt2   = (short*)(ws + 3538944);               // [1408][512]
  short* Wt3   = (short*)(ws + 4980736);               // [512][1408]
  float* tv    = (float*)(ws + 6422528);               // [32][2048]
  short* h     = (short*)(ws + 6684672);               // [8192][512]
  short* qb    = (short*)(ws + 15073280);              // 8 MB
  short* kb    = (short*)(ws + 23461888);              // 8 MB
  short* vbt   = (short*)(ws + 31850496);              // 8 MB  [bh][hd][n]
  short* o     = h;                                    // alias: h dead after qkv
  short* h2    = h;                                    // alias: o dead after wo
  short* ff    = qb;                                   // alias: q/k/v dead after attn
  float* x1    = (float*)d_out;                        // f32 [8192][512] = d_out

  // blocks: [0,3136) weights, [3136,3392) coord proj, [3392,11584) LN1
  convT_all<<<dim3(11584), dim3(256), 0, stream>>>(Wqkv, Wo, W1, W2, W3,
      Wtqkv, Wto, Wt1, Wt2, Wt3, coords, Wc, tv, x, ln1_w, ln1_b, h);
  qkv_gemm<<<dim3(12,64), dim3(256), 0, stream>>>(h, Wtqkv, bqkv, qb, kb, vbt);
  attn_mfma<<<dim3(16,8,4), dim3(256), 0, stream>>>(qb, kb, vbt, tv, o);
  gemm64<<<dim3(8,64), dim3(256), 0, stream>>>(o, 512, Wto, 512, bo, x, x1);
  ln_kernel<<<dim3(ROWS_), dim3(256), 0, stream>>>(x1, ln2_w, ln2_b, h2);
  gate_gemm<<<dim3(22,64), dim3(256), 0, stream>>>(h2, Wt1, Wt2, b1, b2, ff);
  gemm64<<<dim3(8,64), dim3(256), 0, stream>>>(ff, HIDP, Wt3, HIDP, b3, x1, x1);
}